// Round 6
// baseline (121.192 us; speedup 1.0000x reference)
//
#include <hip/hip_runtime.h>
#include <hip/hip_bf16.h>

#define B_TOTAL 16384
#define EMB 128
#define TPB 256
#define NBLK 512            // 512 blocks * 4 waves * 8 rows = 16384
#define KG_LAMBDA 1e-5f
#define FRAG_DW 16384       // 64 fragments * 256 dwords (64 lanes * 16B)
#define SVEC_DW 768
#define IMG_DW (FRAG_DW + SVEC_DW)   // 17152 dwords = 67*256
#define PREP_BLOCKS (IMG_DW / 256)   // 67

typedef float f32x4 __attribute__((ext_vector_type(4)));
typedef unsigned u32x4 __attribute__((ext_vector_type(4)));
typedef __bf16 bf16x8 __attribute__((ext_vector_type(8)));

// RNE float->bf16, packed pair (a in low 16, b in high 16)
__device__ __forceinline__ unsigned pack_bf16x2(float a, float b) {
  unsigned ua = __float_as_uint(a);
  unsigned ub = __float_as_uint(b);
  ua = (ua + 0x7fffu + ((ua >> 16) & 1u)) >> 16;
  ub = (ub + 0x7fffu + ((ub >> 16) & 1u)) >> 16;
  return ua | (ub << 16);
}

// Build fragment-ordered W image + svec in d_ws; also zero d_out.
// frag dword layout: [(t*8+n)*256 + l*4 + w] = bf16pair(W[k0][c], W[k0+1][c])
//   where c = n*16 + (l&15), k0 = t*32 + (l>>4)*8 + 2*w.
// Thread mapping (kp = idx>>7, c = idx&127) makes READS coalesced.
__global__ __launch_bounds__(256) void sur_prep(
    const float* __restrict__ W,
    const float* __restrict__ htw1, const float* __restrict__ htw2,
    const float* __restrict__ hbias,
    const float* __restrict__ rtw1, const float* __restrict__ rtw2,
    const float* __restrict__ rbias,
    unsigned* __restrict__ img, float* __restrict__ out) {
  const int idx = blockIdx.x * 256 + threadIdx.x;  // [0, IMG_DW)
  if (idx < FRAG_DW) {
    const int kp = idx >> 7;          // k-pair 0..127
    const int c  = idx & 127;         // W column
    const float f0 = W[(2 * kp) * EMB + c];       // coalesced across threads
    const float f1 = W[(2 * kp + 1) * EMB + c];
    const int t  = kp >> 4;
    const int rm = kp & 15;
    const int q8 = rm >> 2;
    const int w  = rm & 3;
    const int n  = c >> 4;
    const int ri = c & 15;
    const int l  = q8 * 16 + ri;
    img[((t * 8 + n) << 8) + (l << 2) + w] = pack_bf16x2(f0, f1);
  } else {
    const int j = idx - FRAG_DW;      // 0..767
    const int vsel = j >> 7, cc = j & 127;
    const float* src = vsel == 0 ? htw1 : vsel == 1 ? htw2 : vsel == 2 ? hbias
                     : vsel == 3 ? rtw1 : vsel == 4 ? rtw2 : rbias;
    img[idx] = __float_as_uint(src[cc]);
    if (j == 0) out[0] = 0.f;         // replaces the memset launch
  }
}

__global__ __launch_bounds__(TPB, 2) void sur_fused(
    const int* __restrict__ h, const int* __restrict__ r,
    const int* __restrict__ pos_t, const int* __restrict__ neg_t,
    const float* __restrict__ ent, const float* __restrict__ rel,
    const unsigned* __restrict__ img, float* __restrict__ out) {
  __shared__ float redbuf[2][4];

  const int tid = threadIdx.x;
  const int lane = tid & 63;
  const int wave = tid >> 6;
  const int ri = lane & 15;    // A-row (rows 8..15 duplicate 0..7) / B-col in tile
  const int q = lane >> 4;     // k-chunk selector

  // ---- this wave's 8 rows; issue all index loads immediately ----
  const int rowbase = (blockIdx.x * 4 + wave) * 8;
  const int arow = ri & 7;     // duplicate upper A-rows onto real rows (merged loads)
  const int hidx = h[rowbase + arow] * EMB;
  const int ridx = r[rowbase + arow] * EMB;
  const int qq = q & 1;        // lanes q>=2 duplicate q<2 (merged loads, masked later)
  int pidx[4], nidx[4];
  #pragma unroll
  for (int g = 0; g < 4; ++g) {
    const int rr = rowbase + qq * 4 + g;
    pidx[g] = pos_t[rr] * EMB;
    nidx[g] = neg_t[rr] * EMB;
  }

  const float* svec = (const float*)(img + FRAG_DW);  // 3 KB, L1/L2-hot

  // ---- gather h_e, r_e (this lane's 32 k-columns of its row) ----
  float he[4][8], re[4][8];
  #pragma unroll
  for (int kt = 0; kt < 4; ++kt) {
    const int c0 = kt * 32 + q * 8;
    const float4 a0 = *reinterpret_cast<const float4*>(ent + hidx + c0);
    const float4 a1 = *reinterpret_cast<const float4*>(ent + hidx + c0 + 4);
    const float4 b0 = *reinterpret_cast<const float4*>(rel + ridx + c0);
    const float4 b1 = *reinterpret_cast<const float4*>(rel + ridx + c0 + 4);
    he[kt][0] = a0.x; he[kt][1] = a0.y; he[kt][2] = a0.z; he[kt][3] = a0.w;
    he[kt][4] = a1.x; he[kt][5] = a1.y; he[kt][6] = a1.z; he[kt][7] = a1.w;
    re[kt][0] = b0.x; re[kt][1] = b0.y; re[kt][2] = b0.z; re[kt][3] = b0.w;
    re[kt][4] = b1.x; re[kt][5] = b1.y; re[kt][6] = b1.z; re[kt][7] = b1.w;
  }

  // ---- four per-row dots (partials over 32 cols; reduce over q bits) ----
  float prw1 = 0.f, prw2 = 0.f, phw1 = 0.f, phw2 = 0.f;
  #pragma unroll
  for (int kt = 0; kt < 4; ++kt) {
    const int c0 = kt * 32 + q * 8;
    const float4 w1a = *reinterpret_cast<const float4*>(svec + 0 * 128 + c0);
    const float4 w1b = *reinterpret_cast<const float4*>(svec + 0 * 128 + c0 + 4);
    const float4 w2a = *reinterpret_cast<const float4*>(svec + 1 * 128 + c0);
    const float4 w2b = *reinterpret_cast<const float4*>(svec + 1 * 128 + c0 + 4);
    const float4 v1a = *reinterpret_cast<const float4*>(svec + 3 * 128 + c0);
    const float4 v1b = *reinterpret_cast<const float4*>(svec + 3 * 128 + c0 + 4);
    const float4 v2a = *reinterpret_cast<const float4*>(svec + 4 * 128 + c0);
    const float4 v2b = *reinterpret_cast<const float4*>(svec + 4 * 128 + c0 + 4);
    #pragma unroll
    for (int j = 0; j < 4; ++j) {
      prw1 = fmaf(re[kt][j], (&w1a.x)[j], prw1); prw1 = fmaf(re[kt][j + 4], (&w1b.x)[j], prw1);
      prw2 = fmaf(re[kt][j], (&w2a.x)[j], prw2); prw2 = fmaf(re[kt][j + 4], (&w2b.x)[j], prw2);
      phw1 = fmaf(he[kt][j], (&v1a.x)[j], phw1); phw1 = fmaf(he[kt][j + 4], (&v1b.x)[j], phw1);
      phw2 = fmaf(he[kt][j], (&v2a.x)[j], phw2); phw2 = fmaf(he[kt][j + 4], (&v2b.x)[j], phw2);
    }
  }
  prw1 += __shfl_xor(prw1, 16); prw2 += __shfl_xor(prw2, 16);
  phw1 += __shfl_xor(phw1, 16); phw2 += __shfl_xor(phw2, 16);
  prw1 += __shfl_xor(prw1, 32); prw2 += __shfl_xor(prw2, 32);
  phw1 += __shfl_xor(phw1, 32); phw2 += __shfl_xor(phw2, 32);

  // ---- cross terms -> bf16 A-fragments (l2 masked to the 8 real rows) ----
  const float m8 = (ri < 8) ? 1.f : 0.f;
  float acc_l2 = 0.f;
  u32x4 afu[8];  // [0..3] cross_h K-tiles, [4..7] cross_r K-tiles
  #pragma unroll
  for (int kt = 0; kt < 4; ++kt) {
    const int c0 = kt * 32 + q * 8;
    const float4 hba = *reinterpret_cast<const float4*>(svec + 2 * 128 + c0);
    const float4 hbb = *reinterpret_cast<const float4*>(svec + 2 * 128 + c0 + 4);
    const float4 rba = *reinterpret_cast<const float4*>(svec + 5 * 128 + c0);
    const float4 rbb = *reinterpret_cast<const float4*>(svec + 5 * 128 + c0 + 4);
    float ch[8], cr[8];
    #pragma unroll
    for (int j = 0; j < 8; ++j) {
      const float hb = j < 4 ? (&hba.x)[j] : (&hbb.x)[j - 4];
      const float rb = j < 4 ? (&rba.x)[j] : (&rbb.x)[j - 4];
      ch[j] = fmaf(he[kt][j], prw1, fmaf(re[kt][j], phw2, hb));
      cr[j] = fmaf(he[kt][j], prw2, fmaf(re[kt][j], phw1, rb));
      acc_l2 = fmaf(m8, ch[j] * ch[j] + cr[j] * cr[j], acc_l2);
    }
    #pragma unroll
    for (int d = 0; d < 4; ++d) {
      afu[kt][d]     = pack_bf16x2(ch[2 * d], ch[2 * d + 1]);
      afu[kt + 4][d] = pack_bf16x2(cr[2 * d], cr[2 * d + 1]);
    }
  }

  // ---- issue pos/neg gathers (in flight under the MFMA loop) ----
  float pe[4][8], ne[4][8];
  #pragma unroll
  for (int g = 0; g < 4; ++g) {
    #pragma unroll
    for (int n = 0; n < 8; ++n) {
      pe[g][n] = ent[pidx[g] + n * 16 + ri];  // pred C-layout col = 16n + ri
      ne[g][n] = ent[nidx[g] + n * 16 + ri];
    }
  }

  // ---- GEMM: 64 MFMAs, B fragments streamed coalesced from global ----
  const u32x4* frag = (const u32x4*)img;  // frag[(t*8+n)*64 + lane]
  f32x4 acc[8];
  #pragma unroll
  for (int n = 0; n < 8; ++n) acc[n] = 0.f;
  #pragma unroll
  for (int t = 0; t < 8; ++t) {
    const bf16x8 av = __builtin_bit_cast(bf16x8, afu[t]);
    #pragma unroll
    for (int n = 0; n < 8; ++n) {
      const bf16x8 bv = __builtin_bit_cast(bf16x8, frag[(t * 8 + n) * 64 + lane]);
      acc[n] = __builtin_amdgcn_mfma_f32_16x16x32_bf16(av, bv, acc[n], 0, 0, 0);
    }
  }

  // ---- scores: rows q*4+g valid for q<2; reduce over ri bits ----
  const float mq = (q < 2) ? 1.f : 0.f;
  float sp[4] = {0.f, 0.f, 0.f, 0.f}, sn[4] = {0.f, 0.f, 0.f, 0.f};
  #pragma unroll
  for (int n = 0; n < 8; ++n) {
    #pragma unroll
    for (int g = 0; g < 4; ++g) {
      sp[g] = fmaf(acc[n][g], pe[g][n], sp[g]);
      sn[g] = fmaf(acc[n][g], ne[g][n], sn[g]);
      acc_l2 = fmaf(mq, pe[g][n] * pe[g][n] + ne[g][n] * ne[g][n], acc_l2);
    }
  }
  #pragma unroll
  for (int m = 1; m < 16; m <<= 1) {
    #pragma unroll
    for (int g = 0; g < 4; ++g) {
      sp[g] += __shfl_xor(sp[g], m);
      sn[g] += __shfl_xor(sn[g], m);
    }
  }
  float acc_kg = 0.f;
  if (ri == 0 && q < 2) {
    #pragma unroll
    for (int g = 0; g < 4; ++g) {
      const float x = sn[g] - sp[g];  // == -(pos - neg)
      acc_kg += fmaxf(x, 0.f) + log1pf(expf(-fabsf(x)));
    }
  }

  // ---- wave + block reduction, one atomic per block ----
  float kg = acc_kg, l2 = acc_l2;
  #pragma unroll
  for (int m = 1; m < 64; m <<= 1) {
    kg += __shfl_xor(kg, m);
    l2 += __shfl_xor(l2, m);
  }
  if (lane == 0) { redbuf[0][wave] = kg; redbuf[1][wave] = l2; }
  __syncthreads();
  if (tid == 0) {
    const float K = redbuf[0][0] + redbuf[0][1] + redbuf[0][2] + redbuf[0][3];
    const float L = redbuf[1][0] + redbuf[1][1] + redbuf[1][2] + redbuf[1][3];
    atomicAdd(out, (K + KG_LAMBDA * 0.5f * L) * (1.0f / (float)B_TOTAL));
  }
}

extern "C" void kernel_launch(void* const* d_in, const int* in_sizes, int n_in,
                              void* d_out, int out_size, void* d_ws, size_t ws_size,
                              hipStream_t stream) {
  const int* h     = (const int*)d_in[0];
  const int* r     = (const int*)d_in[1];
  const int* pos_t = (const int*)d_in[2];
  const int* neg_t = (const int*)d_in[3];
  const float* ent  = (const float*)d_in[4];
  const float* rel  = (const float*)d_in[5];
  const float* htw1 = (const float*)d_in[6];
  const float* htw2 = (const float*)d_in[7];
  const float* hb   = (const float*)d_in[8];
  const float* rtw1 = (const float*)d_in[9];
  const float* rtw2 = (const float*)d_in[10];
  const float* rb   = (const float*)d_in[11];
  const float* W    = (const float*)d_in[12];
  unsigned* img = (unsigned*)d_ws;
  float* out = (float*)d_out;

  hipLaunchKernelGGL(sur_prep, dim3(PREP_BLOCKS), dim3(256), 0, stream,
                     W, htw1, htw2, hb, rtw1, rtw2, rb, img, out);
  hipLaunchKernelGGL(sur_fused, dim3(NBLK), dim3(TPB), 0, stream,
                     h, r, pos_t, neg_t, ent, rel, img, out);
}

// Round 7
// 118.349 us; speedup vs baseline: 1.0240x; 1.0240x over previous
//
#include <hip/hip_runtime.h>
#include <hip/hip_bf16.h>

#define B_TOTAL 16384
#define EMB 128
#define TPB 256
#define NBLK 512            // 512 blocks * 4 waves * 8 rows = 16384
#define KG_LAMBDA 1e-5f
#define WT_STRIDE 264       // bf16 elems per Wt row (256 + 8 pad = 528 B)
#define IMG_BYTES 73728     // Wt (67584) + svec (3072) + pad -> 18*4096
#define IMG_DW (IMG_BYTES / 4)
#define WT_DW 16896         // 128 rows * 132 dwords
#define SVEC_BYTE_OFF 67584 // WT_DW*4
#define PREDL_STRIDE 132    // floats per pred row (128 + 4 pad)

typedef float f32x4 __attribute__((ext_vector_type(4)));
typedef unsigned u32x4 __attribute__((ext_vector_type(4)));
typedef __bf16 bf16x8 __attribute__((ext_vector_type(8)));

// RNE float->bf16, packed pair (a in low 16, b in high 16)
__device__ __forceinline__ unsigned pack_bf16x2(float a, float b) {
  unsigned ua = __float_as_uint(a);
  unsigned ub = __float_as_uint(b);
  ua = (ua + 0x7fffu + ((ua >> 16) & 1u)) >> 16;
  ub = (ub + 0x7fffu + ((ub >> 16) & 1u)) >> 16;
  return ua | (ub << 16);
}

// Build LDS image in d_ws: Wt[c][kp] bf16-pairs (c*132+kp dwords), then svec.
// Also zeroes d_out (replaces a memset launch).
__global__ __launch_bounds__(256) void sur_prep(
    const float* __restrict__ W,
    const float* __restrict__ htw1, const float* __restrict__ htw2,
    const float* __restrict__ hbias,
    const float* __restrict__ rtw1, const float* __restrict__ rtw2,
    const float* __restrict__ rbias,
    unsigned* __restrict__ img, float* __restrict__ out) {
  const int idx = blockIdx.x * 256 + threadIdx.x;  // [0, IMG_DW)
  if (idx < WT_DW) {
    const int c = idx / 132;          // Wt row (output col)
    const int kp = idx - c * 132;     // k-pair (128 real + 4 pad)
    unsigned v = 0;
    if (kp < 128) {
      const float f0 = W[(2 * kp) * EMB + c];
      const float f1 = W[(2 * kp + 1) * EMB + c];
      v = pack_bf16x2(f0, f1);
    }
    img[idx] = v;
  } else {
    const int j = idx - WT_DW;
    float val = 0.f;
    if (j < 768) {
      const int vsel = j >> 7, cc = j & 127;
      const float* src = vsel == 0 ? htw1 : vsel == 1 ? htw2 : vsel == 2 ? hbias
                       : vsel == 3 ? rtw1 : vsel == 4 ? rtw2 : rbias;
      val = src[cc];
    }
    img[idx] = __float_as_uint(val);
    if (j == 0) out[0] = 0.f;
  }
}

__global__ __launch_bounds__(TPB, 2) void sur_fused(
    const int* __restrict__ h, const int* __restrict__ r,
    const int* __restrict__ pos_t, const int* __restrict__ neg_t,
    const float* __restrict__ ent, const float* __restrict__ rel,
    const unsigned* __restrict__ img, float* __restrict__ out) {
  __shared__ __align__(16) unsigned char smem[IMG_BYTES];
  __shared__ float redbuf[2][4];
  unsigned short (*Wt)[WT_STRIDE] = (unsigned short(*)[WT_STRIDE])smem;
  const float* svec = (const float*)(smem + SVEC_BYTE_OFF);
  float* predL = (float*)smem;  // aliases Wt AFTER the MFMA phase completes

  const int tid = threadIdx.x;
  const int lane = tid & 63;
  const int wave = tid >> 6;
  const int ri = lane & 15;    // A-row slot (rows 8..15 duplicate 0..7) / B-col
  const int q = lane >> 4;     // k-chunk selector
  const int erow = lane >> 3;  // epilogue: this lane's row (0..7)
  const int eseg = lane & 7;   // epilogue: 16-col segment

  // ---- index loads first (longest chains; duplicates merge in coalescer) ----
  const int rowbase = (blockIdx.x * 4 + wave) * 8;
  const int arow = ri & 7;
  const int hidx = h[rowbase + arow] * EMB;
  const int ridx = r[rowbase + arow] * EMB;
  const int pp = pos_t[rowbase + erow] * EMB;
  const int nn = neg_t[rowbase + erow] * EMB;

  // ---- stage prebuilt image -> LDS: 18 coalesced b128 copies/thread ----
  {
    const float4* gsrc = (const float4*)img;
    float4* ldst = (float4*)smem;
    #pragma unroll
    for (int i = 0; i < IMG_BYTES / 16 / TPB; ++i)
      ldst[i * TPB + tid] = gsrc[i * TPB + tid];
  }

  // ---- gather h_e, r_e (this lane's 32 k-columns of its row) ----
  float he[4][8], re[4][8];
  #pragma unroll
  for (int kt = 0; kt < 4; ++kt) {
    const int c0 = kt * 32 + q * 8;
    const float4 a0 = *reinterpret_cast<const float4*>(ent + hidx + c0);
    const float4 a1 = *reinterpret_cast<const float4*>(ent + hidx + c0 + 4);
    const float4 b0 = *reinterpret_cast<const float4*>(rel + ridx + c0);
    const float4 b1 = *reinterpret_cast<const float4*>(rel + ridx + c0 + 4);
    he[kt][0] = a0.x; he[kt][1] = a0.y; he[kt][2] = a0.z; he[kt][3] = a0.w;
    he[kt][4] = a1.x; he[kt][5] = a1.y; he[kt][6] = a1.z; he[kt][7] = a1.w;
    re[kt][0] = b0.x; re[kt][1] = b0.y; re[kt][2] = b0.z; re[kt][3] = b0.w;
    re[kt][4] = b1.x; re[kt][5] = b1.y; re[kt][6] = b1.z; re[kt][7] = b1.w;
  }

  __syncthreads();  // image staged (svec/Wt valid); gathers drained too

  // ---- four per-row dots (partials over 32 cols; reduce over q bits) ----
  float prw1 = 0.f, prw2 = 0.f, phw1 = 0.f, phw2 = 0.f;
  #pragma unroll
  for (int kt = 0; kt < 4; ++kt) {
    const int c0 = kt * 32 + q * 8;
    #pragma unroll
    for (int j = 0; j < 8; ++j) {
      prw1 = fmaf(re[kt][j], svec[0 * 128 + c0 + j], prw1);
      prw2 = fmaf(re[kt][j], svec[1 * 128 + c0 + j], prw2);
      phw1 = fmaf(he[kt][j], svec[3 * 128 + c0 + j], phw1);
      phw2 = fmaf(he[kt][j], svec[4 * 128 + c0 + j], phw2);
    }
  }
  prw1 += __shfl_xor(prw1, 16); prw2 += __shfl_xor(prw2, 16);
  phw1 += __shfl_xor(phw1, 16); phw2 += __shfl_xor(phw2, 16);
  prw1 += __shfl_xor(prw1, 32); prw2 += __shfl_xor(prw2, 32);
  phw1 += __shfl_xor(phw1, 32); phw2 += __shfl_xor(phw2, 32);

  // ---- cross terms -> bf16 A-fragments (l2 masked to the 8 real rows) ----
  const float m8 = (ri < 8) ? 1.f : 0.f;
  float acc_l2 = 0.f;
  u32x4 afu[8];  // [0..3] cross_h K-tiles, [4..7] cross_r K-tiles
  #pragma unroll
  for (int kt = 0; kt < 4; ++kt) {
    const int c0 = kt * 32 + q * 8;
    float ch[8], cr[8];
    #pragma unroll
    for (int j = 0; j < 8; ++j) {
      const float hb = svec[2 * 128 + c0 + j];
      const float rb = svec[5 * 128 + c0 + j];
      ch[j] = fmaf(he[kt][j], prw1, fmaf(re[kt][j], phw2, hb));
      cr[j] = fmaf(he[kt][j], prw2, fmaf(re[kt][j], phw1, rb));
      acc_l2 = fmaf(m8, ch[j] * ch[j] + cr[j] * cr[j], acc_l2);
    }
    #pragma unroll
    for (int d = 0; d < 4; ++d) {
      afu[kt][d]     = pack_bf16x2(ch[2 * d], ch[2 * d + 1]);
      afu[kt + 4][d] = pack_bf16x2(cr[2 * d], cr[2 * d + 1]);
    }
  }

  // ---- GEMM: 64 MFMAs from LDS ----
  f32x4 acc[8];
  #pragma unroll
  for (int n = 0; n < 8; ++n) acc[n] = 0.f;
  #pragma unroll
  for (int t = 0; t < 8; ++t) {
    const bf16x8 av = __builtin_bit_cast(bf16x8, afu[t]);
    #pragma unroll
    for (int n = 0; n < 8; ++n) {
      const bf16x8 bv = *reinterpret_cast<const bf16x8*>(&Wt[n * 16 + ri][t * 32 + q * 8]);
      acc[n] = __builtin_amdgcn_mfma_f32_16x16x32_bf16(av, bv, acc[n], 0, 0, 0);
    }
  }

  // ---- issue pe/ne loads now (coalesced float4; hide under LDS epilogue) ----
  float4 pe4[4], ne4[4];
  #pragma unroll
  for (int j = 0; j < 4; ++j) {
    pe4[j] = *reinterpret_cast<const float4*>(ent + pp + eseg * 16 + j * 4);
    ne4[j] = *reinterpret_cast<const float4*>(ent + nn + eseg * 16 + j * 4);
  }

  __syncthreads();  // all Wt MFMA reads complete -> safe to alias as predL

  // ---- write pred rows 0..7 to predL (q<2 lanes; provably conflict-free) ----
  float* myPred = predL + wave * (8 * PREDL_STRIDE);
  if (q < 2) {
    #pragma unroll
    for (int n = 0; n < 8; ++n) {
      #pragma unroll
      for (int g = 0; g < 4; ++g)
        myPred[(q * 4 + g) * PREDL_STRIDE + n * 16 + ri] = acc[n][g];
    }
  }
  __syncthreads();  // simple, uniform; guarantees predL visible

  // ---- row-contiguous read-back + score dots + pe/ne L2 ----
  float sp = 0.f, sn = 0.f;
  #pragma unroll
  for (int j = 0; j < 4; ++j) {
    const float4 pr = *reinterpret_cast<const float4*>(
        myPred + erow * PREDL_STRIDE + eseg * 16 + j * 4);
    sp += pr.x * pe4[j].x + pr.y * pe4[j].y + pr.z * pe4[j].z + pr.w * pe4[j].w;
    sn += pr.x * ne4[j].x + pr.y * ne4[j].y + pr.z * ne4[j].z + pr.w * ne4[j].w;
    acc_l2 += pe4[j].x * pe4[j].x + pe4[j].y * pe4[j].y
            + pe4[j].z * pe4[j].z + pe4[j].w * pe4[j].w
            + ne4[j].x * ne4[j].x + ne4[j].y * ne4[j].y
            + ne4[j].z * ne4[j].z + ne4[j].w * ne4[j].w;
  }
  sp += __shfl_xor(sp, 1); sn += __shfl_xor(sn, 1);
  sp += __shfl_xor(sp, 2); sn += __shfl_xor(sn, 2);
  sp += __shfl_xor(sp, 4); sn += __shfl_xor(sn, 4);

  float acc_kg = 0.f;
  if (eseg == 0) {
    const float x = sn - sp;  // == -(pos - neg)
    acc_kg = fmaxf(x, 0.f) + log1pf(expf(-fabsf(x)));
  }

  // ---- wave + block reduction, one atomic per block ----
  float kg = acc_kg, l2 = acc_l2;
  #pragma unroll
  for (int m = 1; m < 64; m <<= 1) {
    kg += __shfl_xor(kg, m);
    l2 += __shfl_xor(l2, m);
  }
  if (lane == 0) { redbuf[0][wave] = kg; redbuf[1][wave] = l2; }
  __syncthreads();
  if (tid == 0) {
    const float K = redbuf[0][0] + redbuf[0][1] + redbuf[0][2] + redbuf[0][3];
    const float L = redbuf[1][0] + redbuf[1][1] + redbuf[1][2] + redbuf[1][3];
    atomicAdd(out, (K + KG_LAMBDA * 0.5f * L) * (1.0f / (float)B_TOTAL));
  }
}

extern "C" void kernel_launch(void* const* d_in, const int* in_sizes, int n_in,
                              void* d_out, int out_size, void* d_ws, size_t ws_size,
                              hipStream_t stream) {
  const int* h     = (const int*)d_in[0];
  const int* r     = (const int*)d_in[1];
  const int* pos_t = (const int*)d_in[2];
  const int* neg_t = (const int*)d_in[3];
  const float* ent  = (const float*)d_in[4];
  const float* rel  = (const float*)d_in[5];
  const float* htw1 = (const float*)d_in[6];
  const float* htw2 = (const float*)d_in[7];
  const float* hb   = (const float*)d_in[8];
  const float* rtw1 = (const float*)d_in[9];
  const float* rtw2 = (const float*)d_in[10];
  const float* rb   = (const float*)d_in[11];
  const float* W    = (const float*)d_in[12];
  unsigned* img = (unsigned*)d_ws;
  float* out = (float*)d_out;

  hipLaunchKernelGGL(sur_prep, dim3(IMG_DW / 256), dim3(256), 0, stream,
                     W, htw1, htw2, hb, rtw1, rtw2, rb, img, out);
  hipLaunchKernelGGL(sur_fused, dim3(NBLK), dim3(TPB), 0, stream,
                     h, r, pos_t, neg_t, ent, rel, img, out);
}